// Round 5
// baseline (62.581 us; speedup 1.0000x reference)
//
#include <hip/hip_runtime.h>
#include <math.h>

#define BATCH 8
#define NOBJ  32
#define NANCH 16384
#define NTOT  (BATCH * NANCH)   // 131072

// ---- ws word layout ----
#define S_NPOS 0   // int
#define S_NNEG 1   // int
#define S_BOX  2   // f32 sum
#define S_POS  3   // f32 sum
#define S_WSUM 4   // f32 sum
#define S_K    5   // int
#define S_B1   6   // int (level-1 bucket, 12 bits)
#define S_R    7   // int remaining target within current level
#define S_ACC  8   // f32 sum of fully-taken buckets so far
#define S_DONE 9   // int
#define S_SNEG 10  // f32 final negative sum (when resolved early)
#define S_HB   11  // int combined (b1<<12)|b2 prefix for level 3
#define S_CNT1 12  // arrival counter kernel 2
#define S_CNT2 13  // arrival counter kernel 3
#define S_CNT3 14  // arrival counter kernel 4

#define OFF_SLOTS 64                        // 512 blocks * 8 words
#define OFF_H1C   (OFF_SLOTS + 512 * 8)     // 4096 cnt (top-12-bit buckets)
#define OFF_H1S   (OFF_H1C + 4096)          // 4096 f32 sum
#define OFF_H2C   (OFF_H1S + 4096)          // 4096 cnt (mid-12-bit buckets)
#define OFF_H2S   (OFF_H2C + 4096)          // 4096 f32 sum
#define OFF_H3C   (OFF_H2S + 4096)          // 256 cnt (low-8-bit buckets)
#define OFF_ZERO_BEG OFF_H1C
#define OFF_ZERO_WORDS (4096 * 4 + 256)     // 16640 = 65 blocks * 256
#define OFF_BITS  (OFF_H3C + 256)           // 131072 words, fully rewritten

__device__ __forceinline__ float smooth_l1f(float d) {
    float ad = fabsf(d);
    return ad < 1.0f ? 0.5f * ad * ad : ad - 0.5f;
}

__device__ __forceinline__ unsigned ld_au(const unsigned* p) {
    return __hip_atomic_load(p, __ATOMIC_RELAXED, __HIP_MEMORY_SCOPE_AGENT);
}
__device__ __forceinline__ float ld_af(const float* p) {
    return __hip_atomic_load(p, __ATOMIC_RELAXED, __HIP_MEMORY_SCOPE_AGENT);
}

// Parallel top-k cutoff over 4096 merged buckets (cnt=gq, f32 sum=gv, agent-
// scope loads). target>=1 guaranteed <= total count. Writes result scalars.
// level 1 -> S_B1, level 2 -> S_HB=(b1<<12)|b2. Runs in one 256-thread block.
__device__ __forceinline__ void select4096(
    unsigned int* ws, const unsigned* gq, const float* gv,
    int target, float acc_in, int level, int b1,
    unsigned* hc, float* hs, int* s_c, float* s_s, int t)
{
    // stage buckets into LDS + per-strip totals (strip = 16 buckets)
    int cc = 0; float ssum = 0.f;
#pragma unroll
    for (int i = 0; i < 16; ++i) {
        unsigned c = ld_au(gq + t * 16 + i);
        float    v = ld_af(gv + t * 16 + i);
        hc[t * 16 + i] = c; hs[t * 16 + i] = v;
        cc += (int)c; ssum += v;
    }
    int myc = cc; float mys = ssum;
    s_c[t] = cc; s_s[t] = ssum;
    __syncthreads();
    // reverse inclusive scan: s_c[t] = sum of strips t..255
    for (int d = 1; d < 256; d <<= 1) {
        int   c2 = (t + d < 256) ? s_c[t + d] : 0;
        float v2 = (t + d < 256) ? s_s[t + d] : 0.f;
        __syncthreads();
        s_c[t] += c2; s_s[t] += v2;
        __syncthreads();
    }
    __shared__ int sh_strip, sh_cum; __shared__ float sh_acc;
    int SC = s_c[t]; float SS = s_s[t];
    int SCn = (t < 255) ? s_c[t + 1] : 0;
    bool ok  = (SC >= target);
    bool okn = (t < 255) && (SCn >= target);
    if (ok && !okn) {   // exactly one thread: largest t whose suffix >= target
        sh_strip = t;
        sh_cum = SC - myc;                 // count fully taken above this strip
        sh_acc = acc_in + (SS - mys);      // sum fully taken above this strip
    }
    __syncthreads();
    if (t < 16) {        // lanes 0..15 of wave 0: suffix scan within the strip
        int strip = sh_strip, cum = sh_cum; float acc = sh_acc;
        unsigned cb = hc[strip * 16 + t]; float sb = hs[strip * 16 + t];
        int sc = (int)cb; float sv = sb;
#pragma unroll
        for (int d = 1; d < 16; d <<= 1) {
            int   c2 = __shfl_down(sc, d, 16);
            float v2 = __shfl_down(sv, d, 16);
            if (t + d < 16) { sc += c2; sv += v2; }
        }
        bool okb = (cum + sc >= target);
        int oknbi = __shfl_down((int)okb, 1, 16);
        bool oknb = (t < 15) && (oknbi != 0);
        if (okb && !oknb) {
            int above = cum + sc - (int)cb;
            int rrem = target - above;
            float acc2 = acc + (sv - sb);
            if (rrem == (int)cb) {         // whole bucket taken: resolved
                ((int*)ws)[S_DONE] = 1;
                ((float*)ws)[S_SNEG] = acc2 + sb;
            } else {
                ((int*)ws)[S_DONE] = 0;
                if (level == 1) ((int*)ws)[S_B1] = strip * 16 + t;
                else            ((int*)ws)[S_HB] = (b1 << 12) | (strip * 16 + t);
                ((int*)ws)[S_R] = rrem;
                ((float*)ws)[S_ACC] = acc2;
            }
        }
    }
}

__global__ __launch_bounds__(256) void dl_main(
    const float* __restrict__ pred_boxes,
    const float* __restrict__ pred_classes,
    const float* __restrict__ true_boxes,
    const int*   __restrict__ true_classes,
    const float* __restrict__ anchors,
    unsigned int* __restrict__ ws)
{
    __shared__ float s_tb[NOBJ * 4];
    __shared__ int   s_tc[NOBJ];
    __shared__ int   s_ri[4][2];
    __shared__ float s_rf[4][3];

    // zero histogram regions + arrival counters (consumers run in later kernels)
    if (blockIdx.x < 65) ws[OFF_ZERO_BEG + blockIdx.x * 256 + threadIdx.x] = 0u;
    if (blockIdx.x == 65 && threadIdx.x < 3) ws[S_CNT1 + threadIdx.x] = 0u;

    int idx = blockIdx.x * 256 + threadIdx.x;   // 16384 % 256 == 0: no image straddling
    int b = idx >> 14;
    int a = idx & (NANCH - 1);
    if (threadIdx.x < NOBJ * 4) s_tb[threadIdx.x] = true_boxes[b * NOBJ * 4 + threadIdx.x];
    if (threadIdx.x < NOBJ)     s_tc[threadIdx.x] = true_classes[b * NOBJ + threadIdx.x];
    __syncthreads();

    float4 anc = reinterpret_cast<const float4*>(anchors)[a];   // (cx, cy, w, h)
    float ax1 = anc.x - anc.z * 0.5f;
    float ay1 = anc.y - anc.w * 0.5f;
    float ax2 = anc.x + anc.z * 0.5f;
    float ay2 = anc.y + anc.w * 0.5f;
    float area_a = (ax2 - ax1) * (ay2 - ay1);

    float ov[NOBJ];
    float best = -3.402823466e38f;
#pragma unroll
    for (int o = 0; o < NOBJ; ++o) {
        float v;
        if (s_tc[o] < 0) {
            v = -1.0f;   // reference masks padded slots' overlap to -1
        } else {
            float bx1 = s_tb[o * 4 + 0], by1 = s_tb[o * 4 + 1];
            float bx2 = s_tb[o * 4 + 2], by2 = s_tb[o * 4 + 3];
            float ltx = fmaxf(ax1, bx1), lty = fmaxf(ay1, by1);
            float rbx = fminf(ax2, bx2), rby = fminf(ay2, by2);
            float w = fmaxf(rbx - ltx, 0.0f), h = fmaxf(rby - lty, 0.0f);
            float inter = w * h;
            float area_b = (bx2 - bx1) * (by2 - by1);
            v = inter / (area_a + area_b - inter);
        }
        ov[o] = v;
        best = fmaxf(best, v);
    }

    // log-softmax over 2 classes
    float2 pc = reinterpret_cast<const float2*>(pred_classes)[idx];
    float mx = fmaxf(pc.x, pc.y);
    float lse = mx + logf(expf(pc.x - mx) + expf(pc.y - mx));
    float l0 = pc.x - lse;
    float l1 = pc.y - lse;

    // negative anchor: best gt overlap < 0.5; nce > 0 so float bits order as uint
    unsigned bits = 0xFFFFFFFFu;   // marker: not negative
    int isneg = 0;
    if (best < 0.5f) { bits = __float_as_uint(-l0); isneg = 1; }
    ws[OFF_BITS + idx] = bits;

    // positives: per o, |best - ov| < 1e-6 and ov > 0.5
    float4 pb = reinterpret_cast<const float4*>(pred_boxes)[idx];
    int npos = 0; float boxs = 0.f, poss = 0.f, wsum = 0.f;
#pragma unroll
    for (int o = 0; o < NOBJ; ++o) {
        float v = ov[o];
        if (fabsf(best - v) < 1e-6f && v > 0.5f) {
            ++npos;
            float bx1 = s_tb[o * 4 + 0], by1 = s_tb[o * 4 + 1];
            float bx2 = s_tb[o * 4 + 2], by2 = s_tb[o * 4 + 3];
            float gcx = ((bx1 + bx2) * 0.5f - anc.x) / (0.1f * anc.z);
            float gcy = ((by1 + by2) * 0.5f - anc.y) / (0.1f * anc.w);
            float gw  = logf((bx2 - bx1) / anc.z) / 0.2f;
            float gh  = logf((by2 - by1) / anc.w) / 0.2f;
            boxs += smooth_l1f(pb.x - gcx) + smooth_l1f(pb.y - gcy)
                  + smooth_l1f(pb.z - gw)  + smooth_l1f(pb.w - gh);
            int c = s_tc[o];
            float w = (c == 1) ? 4.0f : 1.0f;
            poss += w * ((c == 1) ? -l1 : -l0);
            wsum += w;
        }
    }

    // block reduction -> private slot (no global atomics)
    int ip = npos, ng = isneg;
    float fb = boxs, fp = poss, fw = wsum;
#pragma unroll
    for (int off = 32; off; off >>= 1) {
        ip += __shfl_down(ip, off);
        ng += __shfl_down(ng, off);
        fb += __shfl_down(fb, off);
        fp += __shfl_down(fp, off);
        fw += __shfl_down(fw, off);
    }
    int wid = threadIdx.x >> 6, lane = threadIdx.x & 63;
    if (lane == 0) {
        s_ri[wid][0] = ip; s_ri[wid][1] = ng;
        s_rf[wid][0] = fb; s_rf[wid][1] = fp; s_rf[wid][2] = fw;
    }
    __syncthreads();
    if (threadIdx.x == 0) {
        int tp = 0, tn = 0; float t2 = 0.f, t3 = 0.f, t4 = 0.f;
        for (int wv = 0; wv < 4; ++wv) {
            tp += s_ri[wv][0]; tn += s_ri[wv][1];
            t2 += s_rf[wv][0]; t3 += s_rf[wv][1]; t4 += s_rf[wv][2];
        }
        int base = OFF_SLOTS + blockIdx.x * 8;
        ((int*)ws)[base + 0] = tp;
        ((int*)ws)[base + 1] = tn;
        ((float*)ws)[base + 2] = t2;
        ((float*)ws)[base + 3] = t3;
        ((float*)ws)[base + 4] = t4;
    }
}

// hist1 (128 blocks) + last-block sel1
__global__ __launch_bounds__(256) void dl_h1s1(unsigned int* __restrict__ ws)
{
    __shared__ unsigned hc[4096];
    __shared__ float    hs[4096];
    __shared__ int      s_c[256];
    __shared__ float    s_s[256];
    __shared__ int      s_last;
    int t = threadIdx.x;
    for (int i = t; i < 4096; i += 256) { hc[i] = 0u; hs[i] = 0.f; }
    __syncthreads();
    int base = blockIdx.x * 1024 + t;
#pragma unroll
    for (int j = 0; j < 4; ++j) {
        unsigned bits = ws[OFF_BITS + base + j * 256];
        if (bits != 0xFFFFFFFFu) {
            atomicAdd(&hc[bits >> 20], 1u);
            atomicAdd(&hs[bits >> 20], __uint_as_float(bits));
        }
    }
    __syncthreads();
    for (int i = t; i < 4096; i += 256) {
        unsigned c = hc[i];
        if (c) {
            atomicAdd(ws + OFF_H1C + i, c);
            atomicAdd((float*)(ws + OFF_H1S) + i, hs[i]);
        }
    }
    __threadfence();
    __syncthreads();
    if (t == 0) s_last = (atomicAdd((int*)ws + S_CNT1, 1) == (int)gridDim.x - 1);
    __syncthreads();
    if (!s_last) return;
    __threadfence();

    // ---- sel1 tail (one block) ----
    int ip = 0, ng = 0; float fb = 0.f, fp = 0.f, fw = 0.f;
    for (int s = t; s < 512; s += 256) {
        int sb = OFF_SLOTS + s * 8;
        ip += ((const int*)ws)[sb + 0];
        ng += ((const int*)ws)[sb + 1];
        fb += ((const float*)ws)[sb + 2];
        fp += ((const float*)ws)[sb + 3];
        fw += ((const float*)ws)[sb + 4];
    }
#pragma unroll
    for (int off = 32; off; off >>= 1) {
        ip += __shfl_down(ip, off);
        ng += __shfl_down(ng, off);
        fb += __shfl_down(fb, off);
        fp += __shfl_down(fp, off);
        fw += __shfl_down(fw, off);
    }
    __shared__ int s_ri[4][2]; __shared__ float s_rf[4][3];
    __shared__ int s_k, s_skip;
    int wid = t >> 6, lane = t & 63;
    if (lane == 0) {
        s_ri[wid][0] = ip; s_ri[wid][1] = ng;
        s_rf[wid][0] = fb; s_rf[wid][1] = fp; s_rf[wid][2] = fw;
    }
    __syncthreads();
    if (t == 0) {
        int n_pos = 0, n_neg = 0; float t2 = 0.f, t3 = 0.f, t4 = 0.f;
        for (int wv = 0; wv < 4; ++wv) {
            n_pos += s_ri[wv][0]; n_neg += s_ri[wv][1];
            t2 += s_rf[wv][0]; t3 += s_rf[wv][1]; t4 += s_rf[wv][2];
        }
        ((int*)ws)[S_NPOS] = n_pos;
        ((int*)ws)[S_NNEG] = n_neg;
        ((float*)ws)[S_BOX]  = t2;
        ((float*)ws)[S_POS]  = t3;
        ((float*)ws)[S_WSUM] = t4;
        long long k10 = 10LL * (long long)n_pos;
        int k = (int)((k10 < (long long)n_neg) ? k10 : (long long)n_neg);
        ((int*)ws)[S_K] = k;
        s_k = k;
        s_skip = (k == 0);
        if (k == 0) { ((int*)ws)[S_DONE] = 1; ((float*)ws)[S_SNEG] = 0.f; }
    }
    __syncthreads();
    if (s_skip) return;
    select4096(ws, ws + OFF_H1C, (const float*)(ws + OFF_H1S),
               s_k, 0.f, 1, 0, hc, hs, s_c, s_s, t);
}

// hist2 within bucket b1 (128 blocks) + last-block sel2
__global__ __launch_bounds__(256) void dl_h2s2(unsigned int* __restrict__ ws)
{
    __shared__ unsigned hc[4096];
    __shared__ float    hs[4096];
    __shared__ int      s_c[256];
    __shared__ float    s_s[256];
    __shared__ int      s_last;
    int t = threadIdx.x;
    int done = ((const int*)ws)[S_DONE];
    int b1   = ((const int*)ws)[S_B1];
    if (!done) {
        for (int i = t; i < 4096; i += 256) { hc[i] = 0u; hs[i] = 0.f; }
        __syncthreads();
        int base = blockIdx.x * 1024 + t;
#pragma unroll
        for (int j = 0; j < 4; ++j) {
            unsigned bits = ws[OFF_BITS + base + j * 256];
            if (bits != 0xFFFFFFFFu && (int)(bits >> 20) == b1) {
                atomicAdd(&hc[(bits >> 8) & 0xFFFu], 1u);
                atomicAdd(&hs[(bits >> 8) & 0xFFFu], __uint_as_float(bits));
            }
        }
        __syncthreads();
        for (int i = t; i < 4096; i += 256) {
            unsigned c = hc[i];
            if (c) {
                atomicAdd(ws + OFF_H2C + i, c);
                atomicAdd((float*)(ws + OFF_H2S) + i, hs[i]);
            }
        }
    }
    __threadfence();
    __syncthreads();
    if (t == 0) s_last = (atomicAdd((int*)ws + S_CNT2, 1) == (int)gridDim.x - 1);
    __syncthreads();
    if (!s_last) return;
    if (done) return;
    __threadfence();
    int r = ((const int*)ws)[S_R];
    float acc = ((const float*)ws)[S_ACC];
    select4096(ws, ws + OFF_H2C, (const float*)(ws + OFF_H2S),
               r, acc, 2, b1, hc, hs, s_c, s_s, t);
}

// hist3 (count-only, low 8 bits within 24-bit prefix) + last-block final
__global__ __launch_bounds__(256) void dl_h3f(unsigned int* __restrict__ ws,
                                              float* __restrict__ out)
{
    __shared__ unsigned hc[256];
    __shared__ int      s_c[256];
    __shared__ float    s_s[256];
    __shared__ int      s_last;
    int t = threadIdx.x;
    int done = ((const int*)ws)[S_DONE];
    int hb   = ((const int*)ws)[S_HB];
    if (!done) {
        hc[t] = 0u;
        __syncthreads();
        int base = blockIdx.x * 1024 + t;
#pragma unroll
        for (int j = 0; j < 4; ++j) {
            unsigned bits = ws[OFF_BITS + base + j * 256];
            if (bits != 0xFFFFFFFFu && (int)(bits >> 8) == hb) {
                atomicAdd(&hc[bits & 0xFFu], 1u);
            }
        }
        __syncthreads();
        if (hc[t]) atomicAdd(ws + OFF_H3C + t, hc[t]);
    }
    __threadfence();
    __syncthreads();
    if (t == 0) s_last = (atomicAdd((int*)ws + S_CNT3, 1) == (int)gridDim.x - 1);
    __syncthreads();
    if (!s_last) return;
    __threadfence();

    // ---- final tail (one block) ----
    int n_pos = ((const int*)ws)[S_NPOS];
    int k     = ((const int*)ws)[S_K];
    float denom = (float)(n_pos > 1 ? n_pos : 1);
    float box_loss = ((const float*)ws)[S_BOX] / denom;
    float pos_sum  = ((const float*)ws)[S_POS];
    float wsum     = ((const float*)ws)[S_WSUM];

    if (done) {
        if (t == 0) {
            float sneg = ((const float*)ws)[S_SNEG];
            float cls_loss = 10.0f * (pos_sum + sneg)
                           / fmaxf(wsum + (float)k, 1e-6f) / denom;
            out[0] = box_loss; out[1] = cls_loss; out[2] = box_loss + cls_loss;
        }
        return;
    }
    int r = ((const int*)ws)[S_R];
    float acc = ((const float*)ws)[S_ACC];
    unsigned c = ld_au(ws + OFF_H3C + t);
    float v = __uint_as_float(((unsigned)hb << 8) | (unsigned)t);
    int myc = (int)c; float mys = (float)c * v;
    s_c[t] = myc; s_s[t] = mys;
    __syncthreads();
    for (int d = 1; d < 256; d <<= 1) {
        int   c2 = (t + d < 256) ? s_c[t + d] : 0;
        float v2 = (t + d < 256) ? s_s[t + d] : 0.f;
        __syncthreads();
        s_c[t] += c2; s_s[t] += v2;
        __syncthreads();
    }
    int SC = s_c[t]; float SS = s_s[t];
    int SCn = (t < 255) ? s_c[t + 1] : 0;
    bool ok  = (SC >= r);
    bool okn = (t < 255) && (SCn >= r);
    if (ok && !okn) {   // exactly one thread
        int above = SC - myc;
        int rrem = r - above;
        float sneg = acc + (SS - mys) + (float)rrem * v;
        float cls_loss = 10.0f * (pos_sum + sneg)
                       / fmaxf(wsum + (float)k, 1e-6f) / denom;
        out[0] = box_loss; out[1] = cls_loss; out[2] = box_loss + cls_loss;
    }
}

extern "C" void kernel_launch(void* const* d_in, const int* in_sizes, int n_in,
                              void* d_out, int out_size, void* d_ws, size_t ws_size,
                              hipStream_t stream)
{
    const float* pred_boxes   = (const float*)d_in[0];
    const float* pred_classes = (const float*)d_in[1];
    const float* true_boxes   = (const float*)d_in[2];
    const int*   true_classes = (const int*)d_in[3];
    const float* anchors      = (const float*)d_in[4];
    unsigned int* ws = (unsigned int*)d_ws;

    dl_main<<<NTOT / 256, 256, 0, stream>>>(pred_boxes, pred_classes, true_boxes,
                                            true_classes, anchors, ws);
    dl_h1s1<<<128, 256, 0, stream>>>(ws);
    dl_h2s2<<<128, 256, 0, stream>>>(ws);
    dl_h3f<<<128, 256, 0, stream>>>(ws, (float*)d_out);
}

// Round 6
// 56.347 us; speedup vs baseline: 1.1106x; 1.1106x over previous
//
#include <hip/hip_runtime.h>
#include <math.h>

#define NOBJ  32
#define NANCH 16384
#define NTOT  131072      // 8 * 16384
#define NB2   128         // blocks in dl_select (16 groups of 8)

// ---- ws word layout ----
#define OFF_SLOTS 64                        // 512 blocks * 8 words
#define OFF_H1C   (OFF_SLOTS + 4096)        // 4096 cnt (top-12-bit buckets)
#define OFF_H1S   (OFF_H1C + 4096)          // 4096 f32 sum
#define OFF_H2C   (OFF_H1S + 4096)          // 4096 cnt (mid-12-bit)
#define OFF_H2S   (OFF_H2C + 4096)          // 4096 f32 sum
#define OFF_H3C   (OFF_H2S + 4096)          // 256 cnt (low-8-bit)
#define OFF_BAR   (OFF_H3C + 256)           // barrier state, 1088 words
#define BAR_GRP   (OFF_BAR)                 // 16 groups * 32-word stride
#define BAR_ROOT  (OFF_BAR + 512)
#define BAR_RGEN  (OFF_BAR + 544)
#define BAR_GGEN  (OFF_BAR + 576)           // 16 groups * 32-word stride
#define OFF_ZERO_BEG OFF_H1C
#define OFF_ZERO_WORDS (4096 * 4 + 256 + 1088)   // 17728
#define OFF_BITS  (OFF_BAR + 1088)          // 131072 words
// total = OFF_BITS + NTOT ~= 612 KB

__device__ __forceinline__ float smooth_l1f(float d) {
    float ad = fabsf(d);
    return ad < 1.0f ? 0.5f * ad * ad : ad - 0.5f;
}

// ---------------- kernel 1: per-anchor compute ----------------
__global__ __launch_bounds__(256) void dl_main(
    const float* __restrict__ pred_boxes,
    const float* __restrict__ pred_classes,
    const float* __restrict__ true_boxes,
    const int*   __restrict__ true_classes,
    const float* __restrict__ anchors,
    unsigned int* __restrict__ ws)
{
    __shared__ float s_tb[NOBJ * 4];
    __shared__ int   s_tc[NOBJ];
    __shared__ int   s_ri[4][2];
    __shared__ float s_rf[4][3];

    // zero hists + barrier state (plain stores; consumers are in kernel 2)
    if (blockIdx.x < 70) {
        int zw = blockIdx.x * 256 + threadIdx.x;
        if (zw < OFF_ZERO_WORDS) ws[OFF_ZERO_BEG + zw] = 0u;
    }

    int idx = blockIdx.x * 256 + threadIdx.x;   // 16384 % 256 == 0: no image straddling
    int b = idx >> 14;
    int a = idx & (NANCH - 1);
    if (threadIdx.x < NOBJ * 4) s_tb[threadIdx.x] = true_boxes[b * NOBJ * 4 + threadIdx.x];
    if (threadIdx.x < NOBJ)     s_tc[threadIdx.x] = true_classes[b * NOBJ + threadIdx.x];
    __syncthreads();

    float4 anc = reinterpret_cast<const float4*>(anchors)[a];   // (cx, cy, w, h)
    float ax1 = anc.x - anc.z * 0.5f;
    float ay1 = anc.y - anc.w * 0.5f;
    float ax2 = anc.x + anc.z * 0.5f;
    float ay2 = anc.y + anc.w * 0.5f;
    float area_a = (ax2 - ax1) * (ay2 - ay1);

    float ov[NOBJ];
    float best = -3.402823466e38f;
#pragma unroll
    for (int o = 0; o < NOBJ; ++o) {
        float v;
        if (s_tc[o] < 0) {
            v = -1.0f;   // reference masks padded slots' overlap to -1
        } else {
            float bx1 = s_tb[o * 4 + 0], by1 = s_tb[o * 4 + 1];
            float bx2 = s_tb[o * 4 + 2], by2 = s_tb[o * 4 + 3];
            float ltx = fmaxf(ax1, bx1), lty = fmaxf(ay1, by1);
            float rbx = fminf(ax2, bx2), rby = fminf(ay2, by2);
            float w = fmaxf(rbx - ltx, 0.0f), h = fmaxf(rby - lty, 0.0f);
            float inter = w * h;
            float area_b = (bx2 - bx1) * (by2 - by1);
            v = inter / (area_a + area_b - inter);
        }
        ov[o] = v;
        best = fmaxf(best, v);
    }

    // log-softmax over 2 classes
    float2 pc = reinterpret_cast<const float2*>(pred_classes)[idx];
    float mx = fmaxf(pc.x, pc.y);
    float lse = mx + logf(expf(pc.x - mx) + expf(pc.y - mx));
    float l0 = pc.x - lse;
    float l1 = pc.y - lse;

    // negative anchor: best gt overlap < 0.5; nce > 0 so float bits order as uint
    unsigned bits = 0xFFFFFFFFu;   // marker: not negative
    int isneg = 0;
    if (best < 0.5f) { bits = __float_as_uint(-l0); isneg = 1; }
    ws[OFF_BITS + idx] = bits;

    // positives: per o, |best - ov| < 1e-6 and ov > 0.5
    float4 pb = reinterpret_cast<const float4*>(pred_boxes)[idx];
    int npos = 0; float boxs = 0.f, poss = 0.f, wsum = 0.f;
#pragma unroll
    for (int o = 0; o < NOBJ; ++o) {
        float v = ov[o];
        if (fabsf(best - v) < 1e-6f && v > 0.5f) {
            ++npos;
            float bx1 = s_tb[o * 4 + 0], by1 = s_tb[o * 4 + 1];
            float bx2 = s_tb[o * 4 + 2], by2 = s_tb[o * 4 + 3];
            float gcx = ((bx1 + bx2) * 0.5f - anc.x) / (0.1f * anc.z);
            float gcy = ((by1 + by2) * 0.5f - anc.y) / (0.1f * anc.w);
            float gw  = logf((bx2 - bx1) / anc.z) / 0.2f;
            float gh  = logf((by2 - by1) / anc.w) / 0.2f;
            boxs += smooth_l1f(pb.x - gcx) + smooth_l1f(pb.y - gcy)
                  + smooth_l1f(pb.z - gw)  + smooth_l1f(pb.w - gh);
            int c = s_tc[o];
            float w = (c == 1) ? 4.0f : 1.0f;
            poss += w * ((c == 1) ? -l1 : -l0);
            wsum += w;
        }
    }

    // block reduction -> private slot (no global atomics)
    int ip = npos, ng = isneg;
    float fb = boxs, fp = poss, fw = wsum;
#pragma unroll
    for (int off = 32; off; off >>= 1) {
        ip += __shfl_down(ip, off);
        ng += __shfl_down(ng, off);
        fb += __shfl_down(fb, off);
        fp += __shfl_down(fp, off);
        fw += __shfl_down(fw, off);
    }
    int wid = threadIdx.x >> 6, lane = threadIdx.x & 63;
    if (lane == 0) {
        s_ri[wid][0] = ip; s_ri[wid][1] = ng;
        s_rf[wid][0] = fb; s_rf[wid][1] = fp; s_rf[wid][2] = fw;
    }
    __syncthreads();
    if (threadIdx.x == 0) {
        int tp = 0, tn = 0; float t2 = 0.f, t3 = 0.f, t4 = 0.f;
        for (int wv = 0; wv < 4; ++wv) {
            tp += s_ri[wv][0]; tn += s_ri[wv][1];
            t2 += s_rf[wv][0]; t3 += s_rf[wv][1]; t4 += s_rf[wv][2];
        }
        int base = OFF_SLOTS + blockIdx.x * 8;
        ((int*)ws)[base + 0] = tp;
        ((int*)ws)[base + 1] = tn;
        ((float*)ws)[base + 2] = t2;
        ((float*)ws)[base + 3] = t3;
        ((float*)ws)[base + 4] = t4;
    }
}

// ---------------- kernel 2: all selection phases ----------------
__device__ __forceinline__ unsigned ld_au(const unsigned* p) {
    return __hip_atomic_load(p, __ATOMIC_RELAXED, __HIP_MEMORY_SCOPE_AGENT);
}

// two-level tree grid barrier; phase = 1,2,3... (counters phase-encoded, never reset)
__device__ __forceinline__ void gbar(unsigned* ws, unsigned phase) {
    __syncthreads();
    if (threadIdx.x == 0) {
        __threadfence();
        int grp = blockIdx.x >> 3;
        unsigned* gcnt = ws + BAR_GRP + grp * 32;
        unsigned arrived = __hip_atomic_fetch_add(gcnt, 1u, __ATOMIC_ACQ_REL,
                                                  __HIP_MEMORY_SCOPE_AGENT) + 1u;
        if (arrived == 8u * phase) {          // last of group -> group leader
            unsigned ra = __hip_atomic_fetch_add(ws + BAR_ROOT, 1u, __ATOMIC_ACQ_REL,
                                                 __HIP_MEMORY_SCOPE_AGENT) + 1u;
            if (ra == 16u * phase) {
                __hip_atomic_store(ws + BAR_RGEN, phase, __ATOMIC_RELEASE,
                                   __HIP_MEMORY_SCOPE_AGENT);
            }
            while (__hip_atomic_load(ws + BAR_RGEN, __ATOMIC_ACQUIRE,
                                     __HIP_MEMORY_SCOPE_AGENT) < phase)
                __builtin_amdgcn_s_sleep(1);
            __hip_atomic_store(ws + BAR_GGEN + grp * 32, phase, __ATOMIC_RELEASE,
                               __HIP_MEMORY_SCOPE_AGENT);
        } else {
            while (__hip_atomic_load(ws + BAR_GGEN + grp * 32, __ATOMIC_ACQUIRE,
                                     __HIP_MEMORY_SCOPE_AGENT) < phase)
                __builtin_amdgcn_s_sleep(1);
        }
    }
    __syncthreads();
}

__global__ __launch_bounds__(256) void dl_select(unsigned int* __restrict__ ws,
                                                 float* __restrict__ out)
{
    __shared__ unsigned hc[4096];
    __shared__ float    hs[4096];
    __shared__ int      s_c[256];
    __shared__ float    s_fv[256];
    __shared__ int      s_wi[4][2];
    __shared__ float    s_wf[4][3];
    __shared__ int      sh_i[8];
    __shared__ float    s4[4];
    int t = threadIdx.x;
    bool b0 = (blockIdx.x == 0);

    // this block's 1024 candidate bit-patterns, kept in registers all phases
    unsigned vb[4];
#pragma unroll
    for (int j = 0; j < 4; ++j) vb[j] = ws[OFF_BITS + blockIdx.x * 1024 + j * 256 + t];

    // ---- phase 1: hist1 (top 12 bits) in LDS, merge to global ----
    for (int i = t; i < 4096; i += 256) { hc[i] = 0u; hs[i] = 0.f; }
    __syncthreads();
#pragma unroll
    for (int j = 0; j < 4; ++j) {
        unsigned bits = vb[j];
        if (bits != 0xFFFFFFFFu) {
            atomicAdd(&hc[bits >> 20], 1u);
            atomicAdd(&hs[bits >> 20], __uint_as_float(bits));
        }
    }
    __syncthreads();
    for (int i = t; i < 4096; i += 256) {
        unsigned c = hc[i];
        if (c) {
            atomicAdd(ws + OFF_H1C + i, c);
            atomicAdd((float*)(ws + OFF_H1S) + i, hs[i]);
        }
    }

    // slots reduce: ints in all blocks; floats only block 0
    int ip = 0, ng = 0; float fb = 0.f, fp = 0.f, fw = 0.f;
    for (int s = t; s < 512; s += 256) {
        const int* sb = (const int*)ws + OFF_SLOTS + s * 8;
        ip += sb[0]; ng += sb[1];
        if (b0) {
            const float* sf = (const float*)sb;
            fb += sf[2]; fp += sf[3]; fw += sf[4];
        }
    }
#pragma unroll
    for (int off = 32; off; off >>= 1) {
        ip += __shfl_down(ip, off); ng += __shfl_down(ng, off);
        fb += __shfl_down(fb, off); fp += __shfl_down(fp, off); fw += __shfl_down(fw, off);
    }
    int wid = t >> 6, lane = t & 63;
    if (lane == 0) {
        s_wi[wid][0] = ip; s_wi[wid][1] = ng;
        s_wf[wid][0] = fb; s_wf[wid][1] = fp; s_wf[wid][2] = fw;
    }
    __syncthreads();
    int n_pos = 0, n_neg = 0; float box_s = 0.f, pos_s = 0.f, w_s = 0.f;
    for (int wv = 0; wv < 4; ++wv) {
        n_pos += s_wi[wv][0]; n_neg += s_wi[wv][1];
        box_s += s_wf[wv][0]; pos_s += s_wf[wv][1]; w_s += s_wf[wv][2];
    }

    gbar(ws, 1u);   // hist1 merged grid-wide

    long long k10 = 10LL * (long long)n_pos;
    int k = (int)((k10 < (long long)n_neg) ? k10 : (long long)n_neg);
    float denom = (float)(n_pos > 1 ? n_pos : 1);
    float box_loss = box_s / denom;

    if (k == 0) {   // grid-uniform
        if (b0 && t == 0) {
            float cls = 10.0f * pos_s / fmaxf(w_s, 1e-6f) / denom;
            out[0] = box_loss; out[1] = cls; out[2] = box_loss + cls;
        }
        return;
    }

    // ---- generic parallel suffix-select over 4096 global int counts ----
    // (identical in every block: int-only -> bitwise identical results)
    auto sel4096 = [&](const unsigned* g, int target) {
        int cc = 0;
        for (int i = 0; i < 16; ++i) cc += (int)g[t * 16 + i];
        int myc = cc;
        s_c[t] = cc;
        __syncthreads();
        for (int d = 1; d < 256; d <<= 1) {
            int c2 = (t + d < 256) ? s_c[t + d] : 0;
            __syncthreads();
            s_c[t] += c2;
            __syncthreads();
        }
        int SC = s_c[t]; int SCn = (t < 255) ? s_c[t + 1] : 0;
        if (SC >= target && !(t < 255 && SCn >= target)) { sh_i[0] = t; sh_i[1] = SC - myc; }
        __syncthreads();
        int strip = sh_i[0], above = sh_i[1];
        if (t < 16) {
            int cb = (int)g[strip * 16 + t];
            int sc = cb;
#pragma unroll
            for (int d = 1; d < 16; d <<= 1) {
                int c2 = __shfl_down(sc, d, 16);
                if (t + d < 16) sc += c2;
            }
            int okb = (above + sc >= target) ? 1 : 0;
            int oknb = __shfl_down(okb, 1, 16);
            if (okb && !(t < 15 && oknb)) {
                sh_i[2] = strip * 16 + t;
                sh_i[3] = target - (above + sc - cb);
                sh_i[4] = cb;
            }
        }
        __syncthreads();
    };

    // block-0-only: sum of float bucket sums strictly above cut
    auto sumAbove = [&](const float* g, int cut) -> float {
        __syncthreads();
        float a = 0.f;
        for (int i = t; i < 4096; i += 256) if (i > cut) a += g[i];
#pragma unroll
        for (int off = 32; off; off >>= 1) a += __shfl_down(a, off);
        if (lane == 0) s4[wid] = a;
        __syncthreads();
        return s4[0] + s4[1] + s4[2] + s4[3];
    };

    // ---- sel1 ----
    sel4096(ws + OFF_H1C, k);
    int b1 = sh_i[2], r1 = sh_i[3], cb1 = sh_i[4];
    float acc = 0.f;
    if (b0) acc = sumAbove((const float*)(ws + OFF_H1S), b1);
    int done = (r1 == cb1);
    if (done) {   // grid-uniform
        if (b0 && t == 0) {
            float sneg = acc + ((const float*)(ws + OFF_H1S))[b1];
            float cls = 10.0f * (pos_s + sneg) / fmaxf(w_s + (float)k, 1e-6f) / denom;
            out[0] = box_loss; out[1] = cls; out[2] = box_loss + cls;
        }
        return;
    }

    // ---- phase 2: hist2 (mid 12 bits within bucket b1) ----
    __syncthreads();
    for (int i = t; i < 4096; i += 256) { hc[i] = 0u; hs[i] = 0.f; }
    __syncthreads();
#pragma unroll
    for (int j = 0; j < 4; ++j) {
        unsigned bits = vb[j];
        if (bits != 0xFFFFFFFFu && (int)(bits >> 20) == b1) {
            atomicAdd(&hc[(bits >> 8) & 0xFFFu], 1u);
            atomicAdd(&hs[(bits >> 8) & 0xFFFu], __uint_as_float(bits));
        }
    }
    __syncthreads();
    for (int i = t; i < 4096; i += 256) {
        unsigned c = hc[i];
        if (c) {
            atomicAdd(ws + OFF_H2C + i, c);
            atomicAdd((float*)(ws + OFF_H2S) + i, hs[i]);
        }
    }
    gbar(ws, 2u);

    // ---- sel2 ----
    sel4096(ws + OFF_H2C, r1);
    int b2 = sh_i[2], r2 = sh_i[3], cb2 = sh_i[4];
    if (b0) acc += sumAbove((const float*)(ws + OFF_H2S), b2);
    done = (r2 == cb2);
    if (done) {   // grid-uniform
        if (b0 && t == 0) {
            float sneg = acc + ((const float*)(ws + OFF_H2S))[b2];
            float cls = 10.0f * (pos_s + sneg) / fmaxf(w_s + (float)k, 1e-6f) / denom;
            out[0] = box_loss; out[1] = cls; out[2] = box_loss + cls;
        }
        return;
    }

    // ---- phase 3: hist3 (count-only, low 8 bits within 24-bit prefix) ----
    unsigned prefix = ((unsigned)b1 << 12) | (unsigned)b2;
    __syncthreads();
    hc[t] = 0u;
    __syncthreads();
#pragma unroll
    for (int j = 0; j < 4; ++j) {
        unsigned bits = vb[j];
        if (bits != 0xFFFFFFFFu && (bits >> 8) == prefix) atomicAdd(&hc[bits & 0xFFu], 1u);
    }
    __syncthreads();
    if (hc[t]) atomicAdd(ws + OFF_H3C + t, hc[t]);
    gbar(ws, 3u);

    // ---- final: block 0 scans 256 buckets (values exact from bit pattern) ----
    if (!b0) return;
    int c = (int)ld_au(ws + OFF_H3C + t);
    float v = __uint_as_float((prefix << 8) | (unsigned)t);
    int myc = c; float mys = (float)c * v;
    s_c[t] = myc; s_fv[t] = mys;
    __syncthreads();
    for (int d = 1; d < 256; d <<= 1) {
        int   c2 = (t + d < 256) ? s_c[t + d]  : 0;
        float v2 = (t + d < 256) ? s_fv[t + d] : 0.f;
        __syncthreads();
        s_c[t] += c2; s_fv[t] += v2;
        __syncthreads();
    }
    int SC = s_c[t]; float SS = s_fv[t];
    int SCn = (t < 255) ? s_c[t + 1] : 0;
    if (SC >= r2 && !(t < 255 && SCn >= r2)) {   // exactly one thread
        int rrem = r2 - (SC - myc);
        float sneg = acc + (SS - mys) + (float)rrem * v;
        float cls = 10.0f * (pos_s + sneg) / fmaxf(w_s + (float)k, 1e-6f) / denom;
        out[0] = box_loss; out[1] = cls; out[2] = box_loss + cls;
    }
}

extern "C" void kernel_launch(void* const* d_in, const int* in_sizes, int n_in,
                              void* d_out, int out_size, void* d_ws, size_t ws_size,
                              hipStream_t stream)
{
    const float* pred_boxes   = (const float*)d_in[0];
    const float* pred_classes = (const float*)d_in[1];
    const float* true_boxes   = (const float*)d_in[2];
    const int*   true_classes = (const int*)d_in[3];
    const float* anchors      = (const float*)d_in[4];
    unsigned int* ws = (unsigned int*)d_ws;

    dl_main<<<NTOT / 256, 256, 0, stream>>>(pred_boxes, pred_classes, true_boxes,
                                            true_classes, anchors, ws);
    dl_select<<<NB2, 256, 0, stream>>>(ws, (float*)d_out);
}

// Round 7
// 33.791 us; speedup vs baseline: 1.8520x; 1.6675x over previous
//
#include <hip/hip_runtime.h>
#include <math.h>

#define NOBJ  32
#define NANCH 16384
#define NTOT  131072      // 8 * 16384
#define NBLK  32          // dl_select blocks
#define MARK  0xFFFFFFFFu

// ---- ws word layout ----
#define OFF_SLOTS 64                 // 512 blocks * 8 words (np, nn, box, pos, wsum)
#define OFF_H1C   4160               // 4 replicas * 4096 cnt (top-12-bit)
#define OFF_H2C   20544              // 4 replicas * 4096 cnt (mid-12-bit)
#define OFF_H3C   36928              // 4 replicas * 256 cnt (low-8-bit)
#define OFF_FLAG  37952              // 32 blocks * 16-word stride (barrier flags)
#define OFF_FSL   38464              // 32 f32 final partial sums
#define OFF_ZERO_BEG  OFF_H1C
#define OFF_ZERO_WORDS 34336         // H1C..FSL inclusive
#define OFF_BITS  38496              // 131072 words, fully rewritten each call
// total = OFF_BITS + NTOT = 169568 words ~= 678 KB (ws proven >= 1.57 MB)

__device__ __forceinline__ float smooth_l1f(float d) {
    float ad = fabsf(d);
    return ad < 1.0f ? 0.5f * ad * ad : ad - 0.5f;
}

// ---------------- kernel 1: per-anchor compute (proven R2-R6) ----------------
__global__ __launch_bounds__(256) void dl_main(
    const float* __restrict__ pred_boxes,
    const float* __restrict__ pred_classes,
    const float* __restrict__ true_boxes,
    const int*   __restrict__ true_classes,
    const float* __restrict__ anchors,
    unsigned int* __restrict__ ws)
{
    __shared__ float s_tb[NOBJ * 4];
    __shared__ int   s_tc[NOBJ];
    __shared__ int   s_ri[4][2];
    __shared__ float s_rf[4][3];

    // zero hist replicas + barrier flags + final slots (consumed by kernel 2)
    if (blockIdx.x < 135) {
        int zw = blockIdx.x * 256 + threadIdx.x;
        if (zw < OFF_ZERO_WORDS) ws[OFF_ZERO_BEG + zw] = 0u;
    }

    int idx = blockIdx.x * 256 + threadIdx.x;   // 16384 % 256 == 0: no image straddling
    int b = idx >> 14;
    int a = idx & (NANCH - 1);
    if (threadIdx.x < NOBJ * 4) s_tb[threadIdx.x] = true_boxes[b * NOBJ * 4 + threadIdx.x];
    if (threadIdx.x < NOBJ)     s_tc[threadIdx.x] = true_classes[b * NOBJ + threadIdx.x];
    __syncthreads();

    float4 anc = reinterpret_cast<const float4*>(anchors)[a];   // (cx, cy, w, h)
    float ax1 = anc.x - anc.z * 0.5f;
    float ay1 = anc.y - anc.w * 0.5f;
    float ax2 = anc.x + anc.z * 0.5f;
    float ay2 = anc.y + anc.w * 0.5f;
    float area_a = (ax2 - ax1) * (ay2 - ay1);

    float ov[NOBJ];
    float best = -3.402823466e38f;
#pragma unroll
    for (int o = 0; o < NOBJ; ++o) {
        float v;
        if (s_tc[o] < 0) {
            v = -1.0f;   // reference masks padded slots' overlap to -1
        } else {
            float bx1 = s_tb[o * 4 + 0], by1 = s_tb[o * 4 + 1];
            float bx2 = s_tb[o * 4 + 2], by2 = s_tb[o * 4 + 3];
            float ltx = fmaxf(ax1, bx1), lty = fmaxf(ay1, by1);
            float rbx = fminf(ax2, bx2), rby = fminf(ay2, by2);
            float w = fmaxf(rbx - ltx, 0.0f), h = fmaxf(rby - lty, 0.0f);
            float inter = w * h;
            float area_b = (bx2 - bx1) * (by2 - by1);
            v = inter / (area_a + area_b - inter);
        }
        ov[o] = v;
        best = fmaxf(best, v);
    }

    // log-softmax over 2 classes
    float2 pc = reinterpret_cast<const float2*>(pred_classes)[idx];
    float mx = fmaxf(pc.x, pc.y);
    float lse = mx + logf(expf(pc.x - mx) + expf(pc.y - mx));
    float l0 = pc.x - lse;
    float l1 = pc.y - lse;

    // negative anchor: best gt overlap < 0.5; nce > 0 so float bits order as uint
    unsigned bits = MARK;
    int isneg = 0;
    if (best < 0.5f) { bits = __float_as_uint(-l0); isneg = 1; }
    ws[OFF_BITS + idx] = bits;

    // positives: per o, |best - ov| < 1e-6 and ov > 0.5
    float4 pb = reinterpret_cast<const float4*>(pred_boxes)[idx];
    int npos = 0; float boxs = 0.f, poss = 0.f, wsum = 0.f;
#pragma unroll
    for (int o = 0; o < NOBJ; ++o) {
        float v = ov[o];
        if (fabsf(best - v) < 1e-6f && v > 0.5f) {
            ++npos;
            float bx1 = s_tb[o * 4 + 0], by1 = s_tb[o * 4 + 1];
            float bx2 = s_tb[o * 4 + 2], by2 = s_tb[o * 4 + 3];
            float gcx = ((bx1 + bx2) * 0.5f - anc.x) / (0.1f * anc.z);
            float gcy = ((by1 + by2) * 0.5f - anc.y) / (0.1f * anc.w);
            float gw  = logf((bx2 - bx1) / anc.z) / 0.2f;
            float gh  = logf((by2 - by1) / anc.w) / 0.2f;
            boxs += smooth_l1f(pb.x - gcx) + smooth_l1f(pb.y - gcy)
                  + smooth_l1f(pb.z - gw)  + smooth_l1f(pb.w - gh);
            int c = s_tc[o];
            float w = (c == 1) ? 4.0f : 1.0f;
            poss += w * ((c == 1) ? -l1 : -l0);
            wsum += w;
        }
    }

    // block reduction -> private slot (no global atomics)
    int ip = npos, ng = isneg;
    float fb = boxs, fp = poss, fw = wsum;
#pragma unroll
    for (int off = 32; off; off >>= 1) {
        ip += __shfl_down(ip, off);
        ng += __shfl_down(ng, off);
        fb += __shfl_down(fb, off);
        fp += __shfl_down(fp, off);
        fw += __shfl_down(fw, off);
    }
    int wid = threadIdx.x >> 6, lane = threadIdx.x & 63;
    if (lane == 0) {
        s_ri[wid][0] = ip; s_ri[wid][1] = ng;
        s_rf[wid][0] = fb; s_rf[wid][1] = fp; s_rf[wid][2] = fw;
    }
    __syncthreads();
    if (threadIdx.x == 0) {
        int tp = 0, tn = 0; float t2 = 0.f, t3 = 0.f, t4 = 0.f;
        for (int wv = 0; wv < 4; ++wv) {
            tp += s_ri[wv][0]; tn += s_ri[wv][1];
            t2 += s_rf[wv][0]; t3 += s_rf[wv][1]; t4 += s_rf[wv][2];
        }
        int base = OFF_SLOTS + blockIdx.x * 8;
        ((int*)ws)[base + 0] = tp;
        ((int*)ws)[base + 1] = tn;
        ((float*)ws)[base + 2] = t2;
        ((float*)ws)[base + 3] = t3;
        ((float*)ws)[base + 4] = t4;
    }
}

// ---------------- kernel 2: selection, 32 co-resident blocks ----------------

// flag-broadcast grid barrier: no atomic RMW, each block owns one flag line
__device__ __forceinline__ void gbar(unsigned* ws, unsigned phase) {
    __syncthreads();
    if (threadIdx.x < 64) {
        if (threadIdx.x == 0) {
            __threadfence();
            __hip_atomic_store(ws + OFF_FLAG + blockIdx.x * 16, phase,
                               __ATOMIC_RELEASE, __HIP_MEMORY_SCOPE_AGENT);
        }
        bool ok;
        do {
            unsigned v = (threadIdx.x < NBLK)
                ? __hip_atomic_load(ws + OFF_FLAG + threadIdx.x * 16,
                                    __ATOMIC_ACQUIRE, __HIP_MEMORY_SCOPE_AGENT)
                : phase;
            ok = __all(v >= phase);
            if (!ok) __builtin_amdgcn_s_sleep(1);
        } while (!ok);
    }
    __syncthreads();
}

__global__ __launch_bounds__(1024) void dl_select(unsigned int* __restrict__ ws,
                                                  float* __restrict__ out)
{
    __shared__ unsigned hrep[4][4096];   // 64 KB replicated count hist
    __shared__ unsigned hsum[4096];      // merged counts for cutoff walk
    __shared__ int      s_c[1024];
    __shared__ int      s_wi[16][2];
    __shared__ float    s_wf[16][3];
    __shared__ int      sh[4];

    const int t = threadIdx.x, wave = t >> 6, lane = t & 63, rep = wave >> 2;
    const bool b0 = (blockIdx.x == 0);
    unsigned* hflat = &hrep[0][0];

    // this block's 4096 candidates, 4 per thread, kept in registers all phases
    uint4 v4 = *reinterpret_cast<const uint4*>(ws + OFF_BITS + blockIdx.x * 4096 + t * 4);
    unsigned vb[4] = { v4.x, v4.y, v4.z, v4.w };

    // zero LDS hist replicas
    for (int i = t; i < 16384; i += 1024) hflat[i] = 0u;

    // reduce dl_main slots (all blocks redundantly -> grid-uniform decisions)
    int np = 0, nn = 0; float fb = 0.f, fp = 0.f, fw = 0.f;
    for (int s = t; s < 512; s += 1024) {
        const unsigned* sl = ws + OFF_SLOTS + s * 8;
        np += (int)sl[0]; nn += (int)sl[1];
        fb += __uint_as_float(sl[2]); fp += __uint_as_float(sl[3]); fw += __uint_as_float(sl[4]);
    }
#pragma unroll
    for (int o = 32; o; o >>= 1) {
        np += __shfl_down(np, o); nn += __shfl_down(nn, o);
        fb += __shfl_down(fb, o); fp += __shfl_down(fp, o); fw += __shfl_down(fw, o);
    }
    if (lane == 0) {
        s_wi[wave][0] = np; s_wi[wave][1] = nn;
        s_wf[wave][0] = fb; s_wf[wave][1] = fp; s_wf[wave][2] = fw;
    }
    __syncthreads();   // also covers hflat zeroing before P1 atomics
    np = 0; nn = 0; fb = fp = fw = 0.f;
    for (int w = 0; w < 16; ++w) {
        np += s_wi[w][0]; nn += s_wi[w][1];
        fb += s_wf[w][0]; fp += s_wf[w][1]; fw += s_wf[w][2];
    }

    long long k10 = 10LL * (long long)np;
    int k = (int)((k10 < (long long)nn) ? k10 : (long long)nn);
    float denom = (float)(np > 1 ? np : 1);
    float box_loss = fb / denom;

    if (k == 0) {   // grid-uniform: no barriers touched
        if (b0 && t == 0) {
            float cls = 10.0f * fp / fmaxf(fw, 1e-6f) / denom;
            out[0] = box_loss; out[1] = cls; out[2] = box_loss + cls;
        }
        return;
    }

    // ---- P1: top-12-bit count hist, LDS replicated, merge to global replica ----
#pragma unroll
    for (int j = 0; j < 4; ++j) {
        unsigned b = vb[j];
        if (b != MARK) atomicAdd(&hrep[rep][b >> 20], 1u);
    }
    __syncthreads();
    {
        unsigned* g = ws + OFF_H1C + (blockIdx.x & 3) * 4096;
#pragma unroll
        for (int i = 0; i < 4; ++i) {
            int bkt = t * 4 + i;
            unsigned c = hrep[0][bkt] + hrep[1][bkt] + hrep[2][bkt] + hrep[3][bkt];
            if (c) atomicAdd(g + bkt, c);   // chains <= 8 deep (8 blocks/replica)
        }
    }
    unsigned phase = 1;
    gbar(ws, phase);

    // parallel cutoff select over 4096 merged buckets (identical in all blocks)
    auto sel12 = [&](int off, int target) {
        unsigned c4[4] = {0u, 0u, 0u, 0u};
#pragma unroll
        for (int r = 0; r < 4; ++r) {
            uint4 u = reinterpret_cast<const uint4*>(ws + off + r * 4096)[t];
            c4[0] += u.x; c4[1] += u.y; c4[2] += u.z; c4[3] += u.w;
        }
        int cc = 0;
#pragma unroll
        for (int i = 0; i < 4; ++i) { hsum[t * 4 + i] = c4[i]; cc += (int)c4[i]; }
        int myc = cc;
        s_c[t] = cc;
        __syncthreads();
        for (int d = 1; d < 1024; d <<= 1) {       // reverse inclusive scan
            int c2 = (t + d < 1024) ? s_c[t + d] : 0;
            __syncthreads();
            s_c[t] += c2;
            __syncthreads();
        }
        int SC = s_c[t], SCn = (t < 1023) ? s_c[t + 1] : 0;
        if (SC >= target && !(t < 1023 && SCn >= target)) {   // exactly one thread
            int cum = SC - myc;                                // count above strip
            for (int b = t * 4 + 3; ; --b) {
                int cb = (int)hsum[b];
                if (cum + cb >= target) { sh[0] = b; sh[1] = target - cum; sh[2] = cb; break; }
                cum += cb;
            }
        }
        __syncthreads();
    };

    sel12(OFF_H1C, k);
    int b1 = sh[0], r1 = sh[1];
    unsigned THR = 0; int ge = 0, rrem = 0, resolved = 0;
    if (sh[1] == sh[2]) { THR = (unsigned)b1 << 20; ge = 1; resolved = 1; }

    if (!resolved) {
        // ---- P2: mid-12-bit hist within bucket b1 ----
        for (int i = t; i < 16384; i += 1024) hflat[i] = 0u;
        __syncthreads();
#pragma unroll
        for (int j = 0; j < 4; ++j) {
            unsigned b = vb[j];   // marker top12 = 4095 > any valid (<= 2039)
            if ((int)(b >> 20) == b1) atomicAdd(&hrep[rep][(b >> 8) & 0xFFFu], 1u);
        }
        __syncthreads();
        {
            unsigned* g = ws + OFF_H2C + (blockIdx.x & 3) * 4096;
#pragma unroll
            for (int i = 0; i < 4; ++i) {
                int bkt = t * 4 + i;
                unsigned c = hrep[0][bkt] + hrep[1][bkt] + hrep[2][bkt] + hrep[3][bkt];
                if (c) atomicAdd(g + bkt, c);
            }
        }
        gbar(ws, ++phase);
        sel12(OFF_H2C, r1);
        int b2 = sh[0], r2 = sh[1];
        unsigned pfx = ((unsigned)b1 << 12) | (unsigned)b2;
        if (sh[1] == sh[2]) { THR = pfx << 8; ge = 1; resolved = 1; }

        if (!resolved) {
            // ---- P3: low-8-bit hist within 24-bit prefix ----
            for (int i = t; i < 16384; i += 1024) hflat[i] = 0u;
            __syncthreads();
#pragma unroll
            for (int j = 0; j < 4; ++j) {
                unsigned b = vb[j];
                if ((b >> 8) == pfx) atomicAdd(&hrep[rep][b & 0xFFu], 1u);
            }
            __syncthreads();
            {
                unsigned* g3 = ws + OFF_H3C + (blockIdx.x & 3) * 256;
                if (t < 256) {
                    unsigned c = hrep[0][t] + hrep[1][t] + hrep[2][t] + hrep[3][t];
                    if (c) atomicAdd(g3 + t, c);
                }
            }
            gbar(ws, ++phase);
            int c = 0;
            if (t < 256)
                for (int r = 0; r < 4; ++r) c += (int)ws[OFF_H3C + r * 256 + t];
            int myc = c;
            s_c[t] = c;
            __syncthreads();
            for (int d = 1; d < 1024; d <<= 1) {
                int c2 = (t + d < 1024) ? s_c[t + d] : 0;
                __syncthreads();
                s_c[t] += c2;
                __syncthreads();
            }
            int SC = s_c[t], SCn = (t < 1023) ? s_c[t + 1] : 0;
            if (SC >= r2 && !(t < 1023 && SCn >= r2)) { sh[0] = t; sh[1] = r2 - (SC - myc); }
            __syncthreads();
            THR = (pfx << 8) | (unsigned)sh[0];
            rrem = sh[1];
            ge = 0;
        }
    }

    // ---- FINAL: per-block register sum of selected candidates ----
    float loc = 0.f;
#pragma unroll
    for (int j = 0; j < 4; ++j) {
        unsigned b = vb[j];
        if (b != MARK && (ge ? (b >= THR) : (b > THR))) loc += __uint_as_float(b);
    }
#pragma unroll
    for (int o = 32; o; o >>= 1) loc += __shfl_down(loc, o);
    if (lane == 0) s_wf[wave][0] = loc;
    __syncthreads();
    if (t == 0) {
        float s = 0.f;
        for (int w = 0; w < 16; ++w) s += s_wf[w][0];
        ((float*)ws)[OFF_FSL + blockIdx.x] = s;
    }
    gbar(ws, ++phase);
    if (b0 && t < 64) {
        float s = (t < NBLK) ? ((const float*)ws)[OFF_FSL + t] : 0.f;
#pragma unroll
        for (int o = 32; o; o >>= 1) s += __shfl_down(s, o);
        if (t == 0) {
            float sneg = s + (ge ? 0.f : (float)rrem * __uint_as_float(THR));
            float cls = 10.0f * (fp + sneg) / fmaxf(fw + (float)k, 1e-6f) / denom;
            out[0] = box_loss; out[1] = cls; out[2] = box_loss + cls;
        }
    }
}

extern "C" void kernel_launch(void* const* d_in, const int* in_sizes, int n_in,
                              void* d_out, int out_size, void* d_ws, size_t ws_size,
                              hipStream_t stream)
{
    const float* pred_boxes   = (const float*)d_in[0];
    const float* pred_classes = (const float*)d_in[1];
    const float* true_boxes   = (const float*)d_in[2];
    const int*   true_classes = (const int*)d_in[3];
    const float* anchors      = (const float*)d_in[4];
    unsigned int* ws = (unsigned int*)d_ws;

    dl_main<<<NTOT / 256, 256, 0, stream>>>(pred_boxes, pred_classes, true_boxes,
                                            true_classes, anchors, ws);
    dl_select<<<NBLK, 1024, 0, stream>>>(ws, (float*)d_out);
}

// Round 8
// 31.268 us; speedup vs baseline: 2.0015x; 1.0807x over previous
//
#include <hip/hip_runtime.h>
#include <math.h>

#define NOBJ  32
#define NANCH 16384
#define NTOT  131072      // 8 * 16384
#define NBLK  16          // dl_select blocks
#define MARK  0xFFFFFFFFu

// ---- ws word layout ----
#define OFF_SLOTS 64                 // 512 blocks * 8 words (np, nn, box, pos, wsum)
#define OFF_H1C   4160               // 4 replicas * 4096 cnt (top-12-bit)
#define OFF_H2C   20544              // 4 replicas * 4096 cnt (mid-12-bit)
#define OFF_H3C   36928              // 4 replicas * 256 cnt (low-8-bit)
#define OFF_FLAG  37952              // 16 blocks * 16-word stride (barrier flags)
#define OFF_FSL   38208              // 16 f32 final partial sums
#define OFF_ZERO_BEG  OFF_H1C
#define OFF_ZERO_WORDS 34064         // H1C..FSL inclusive
#define OFF_BITS  38224              // 131072 words, fully rewritten each call
// total = OFF_BITS + NTOT = 169296 words ~= 677 KB (ws is far larger)

__device__ __forceinline__ float smooth_l1f(float d) {
    float ad = fabsf(d);
    return ad < 1.0f ? 0.5f * ad * ad : ad - 0.5f;
}

// ---------------- kernel 1: per-anchor compute (proven R2-R7) ----------------
__global__ __launch_bounds__(256) void dl_main(
    const float* __restrict__ pred_boxes,
    const float* __restrict__ pred_classes,
    const float* __restrict__ true_boxes,
    const int*   __restrict__ true_classes,
    const float* __restrict__ anchors,
    unsigned int* __restrict__ ws)
{
    __shared__ float s_tb[NOBJ * 4];
    __shared__ int   s_tc[NOBJ];
    __shared__ int   s_ri[4][2];
    __shared__ float s_rf[4][3];

    // zero hist replicas + barrier flags + final slots (consumed by kernel 2)
    if (blockIdx.x < 135) {
        int zw = blockIdx.x * 256 + threadIdx.x;
        if (zw < OFF_ZERO_WORDS) ws[OFF_ZERO_BEG + zw] = 0u;
    }

    int idx = blockIdx.x * 256 + threadIdx.x;   // 16384 % 256 == 0: no image straddling
    int b = idx >> 14;
    int a = idx & (NANCH - 1);
    if (threadIdx.x < NOBJ * 4) s_tb[threadIdx.x] = true_boxes[b * NOBJ * 4 + threadIdx.x];
    if (threadIdx.x < NOBJ)     s_tc[threadIdx.x] = true_classes[b * NOBJ + threadIdx.x];
    __syncthreads();

    float4 anc = reinterpret_cast<const float4*>(anchors)[a];   // (cx, cy, w, h)
    float ax1 = anc.x - anc.z * 0.5f;
    float ay1 = anc.y - anc.w * 0.5f;
    float ax2 = anc.x + anc.z * 0.5f;
    float ay2 = anc.y + anc.w * 0.5f;
    float area_a = (ax2 - ax1) * (ay2 - ay1);

    float ov[NOBJ];
    float best = -3.402823466e38f;
#pragma unroll
    for (int o = 0; o < NOBJ; ++o) {
        float v;
        if (s_tc[o] < 0) {
            v = -1.0f;   // reference masks padded slots' overlap to -1
        } else {
            float bx1 = s_tb[o * 4 + 0], by1 = s_tb[o * 4 + 1];
            float bx2 = s_tb[o * 4 + 2], by2 = s_tb[o * 4 + 3];
            float ltx = fmaxf(ax1, bx1), lty = fmaxf(ay1, by1);
            float rbx = fminf(ax2, bx2), rby = fminf(ay2, by2);
            float w = fmaxf(rbx - ltx, 0.0f), h = fmaxf(rby - lty, 0.0f);
            float inter = w * h;
            float area_b = (bx2 - bx1) * (by2 - by1);
            v = inter / (area_a + area_b - inter);
        }
        ov[o] = v;
        best = fmaxf(best, v);
    }

    // log-softmax over 2 classes
    float2 pc = reinterpret_cast<const float2*>(pred_classes)[idx];
    float mx = fmaxf(pc.x, pc.y);
    float lse = mx + logf(expf(pc.x - mx) + expf(pc.y - mx));
    float l0 = pc.x - lse;
    float l1 = pc.y - lse;

    // negative anchor: best gt overlap < 0.5; nce > 0 so float bits order as uint
    unsigned bits = MARK;
    int isneg = 0;
    if (best < 0.5f) { bits = __float_as_uint(-l0); isneg = 1; }
    ws[OFF_BITS + idx] = bits;

    // positives: per o, |best - ov| < 1e-6 and ov > 0.5
    float4 pb = reinterpret_cast<const float4*>(pred_boxes)[idx];
    int npos = 0; float boxs = 0.f, poss = 0.f, wsum = 0.f;
#pragma unroll
    for (int o = 0; o < NOBJ; ++o) {
        float v = ov[o];
        if (fabsf(best - v) < 1e-6f && v > 0.5f) {
            ++npos;
            float bx1 = s_tb[o * 4 + 0], by1 = s_tb[o * 4 + 1];
            float bx2 = s_tb[o * 4 + 2], by2 = s_tb[o * 4 + 3];
            float gcx = ((bx1 + bx2) * 0.5f - anc.x) / (0.1f * anc.z);
            float gcy = ((by1 + by2) * 0.5f - anc.y) / (0.1f * anc.w);
            float gw  = logf((bx2 - bx1) / anc.z) / 0.2f;
            float gh  = logf((by2 - by1) / anc.w) / 0.2f;
            boxs += smooth_l1f(pb.x - gcx) + smooth_l1f(pb.y - gcy)
                  + smooth_l1f(pb.z - gw)  + smooth_l1f(pb.w - gh);
            int c = s_tc[o];
            float w = (c == 1) ? 4.0f : 1.0f;
            poss += w * ((c == 1) ? -l1 : -l0);
            wsum += w;
        }
    }

    // block reduction -> private slot (no global atomics)
    int ip = npos, ng = isneg;
    float fb = boxs, fp = poss, fw = wsum;
#pragma unroll
    for (int off = 32; off; off >>= 1) {
        ip += __shfl_down(ip, off);
        ng += __shfl_down(ng, off);
        fb += __shfl_down(fb, off);
        fp += __shfl_down(fp, off);
        fw += __shfl_down(fw, off);
    }
    int wid = threadIdx.x >> 6, lane = threadIdx.x & 63;
    if (lane == 0) {
        s_ri[wid][0] = ip; s_ri[wid][1] = ng;
        s_rf[wid][0] = fb; s_rf[wid][1] = fp; s_rf[wid][2] = fw;
    }
    __syncthreads();
    if (threadIdx.x == 0) {
        int tp = 0, tn = 0; float t2 = 0.f, t3 = 0.f, t4 = 0.f;
        for (int wv = 0; wv < 4; ++wv) {
            tp += s_ri[wv][0]; tn += s_ri[wv][1];
            t2 += s_rf[wv][0]; t3 += s_rf[wv][1]; t4 += s_rf[wv][2];
        }
        int base = OFF_SLOTS + blockIdx.x * 8;
        ((int*)ws)[base + 0] = tp;
        ((int*)ws)[base + 1] = tn;
        ((float*)ws)[base + 2] = t2;
        ((float*)ws)[base + 3] = t3;
        ((float*)ws)[base + 4] = t4;
    }
}

// ---------------- kernel 2: selection, 16 co-resident blocks ----------------

// flag-broadcast grid barrier: no atomic RMW, each block owns one flag line
__device__ __forceinline__ void gbar(unsigned* ws, unsigned phase) {
    __syncthreads();
    if (threadIdx.x < 64) {
        if (threadIdx.x == 0) {
            __threadfence();
            __hip_atomic_store(ws + OFF_FLAG + blockIdx.x * 16, phase,
                               __ATOMIC_RELEASE, __HIP_MEMORY_SCOPE_AGENT);
        }
        bool ok;
        do {
            unsigned v = (threadIdx.x < NBLK)
                ? __hip_atomic_load(ws + OFF_FLAG + threadIdx.x * 16,
                                    __ATOMIC_ACQUIRE, __HIP_MEMORY_SCOPE_AGENT)
                : phase;
            ok = __all(v >= phase);
            if (!ok) __builtin_amdgcn_s_sleep(1);
        } while (!ok);
    }
    __syncthreads();
}

__global__ __launch_bounds__(1024) void dl_select(unsigned int* __restrict__ ws,
                                                  float* __restrict__ out)
{
    __shared__ unsigned hrep[4][4096];   // 64 KB replicated count hist
    __shared__ int      wtot[16];
    __shared__ int      s_wi[16][2];
    __shared__ float    s_wf[16][3];
    __shared__ int      sh[4];

    const int t = threadIdx.x, wave = t >> 6, lane = t & 63, rep = wave >> 2;
    const bool b0 = (blockIdx.x == 0);
    unsigned* hflat = &hrep[0][0];

    // this block's 8192 candidates, 8 per thread, kept in registers all phases
    uint4 va = reinterpret_cast<const uint4*>(ws + OFF_BITS + blockIdx.x * 8192)[t * 2];
    uint4 vc = reinterpret_cast<const uint4*>(ws + OFF_BITS + blockIdx.x * 8192)[t * 2 + 1];
    unsigned vb[8] = { va.x, va.y, va.z, va.w, vc.x, vc.y, vc.z, vc.w };

    // zero LDS hist replicas
    for (int i = t; i < 16384; i += 1024) hflat[i] = 0u;

    // reduce dl_main slots (all blocks redundantly -> grid-uniform decisions)
    int np = 0, nn = 0; float fb = 0.f, fp = 0.f, fw = 0.f;
    if (t < 512) {
        const unsigned* sl = ws + OFF_SLOTS + t * 8;
        np = (int)sl[0]; nn = (int)sl[1];
        fb = __uint_as_float(sl[2]); fp = __uint_as_float(sl[3]); fw = __uint_as_float(sl[4]);
    }
#pragma unroll
    for (int o = 32; o; o >>= 1) {
        np += __shfl_down(np, o); nn += __shfl_down(nn, o);
        fb += __shfl_down(fb, o); fp += __shfl_down(fp, o); fw += __shfl_down(fw, o);
    }
    if (lane == 0) {
        s_wi[wave][0] = np; s_wi[wave][1] = nn;
        s_wf[wave][0] = fb; s_wf[wave][1] = fp; s_wf[wave][2] = fw;
    }
    __syncthreads();   // also covers hflat zeroing before P1 atomics
    np = 0; nn = 0; fb = fp = fw = 0.f;
    for (int w = 0; w < 16; ++w) {
        np += s_wi[w][0]; nn += s_wi[w][1];
        fb += s_wf[w][0]; fp += s_wf[w][1]; fw += s_wf[w][2];
    }

    long long k10 = 10LL * (long long)np;
    int k = (int)((k10 < (long long)nn) ? k10 : (long long)nn);
    float denom = (float)(np > 1 ? np : 1);
    float box_loss = fb / denom;

    if (k == 0) {   // grid-uniform: no barriers touched
        if (b0 && t == 0) {
            float cls = 10.0f * fp / fmaxf(fw, 1e-6f) / denom;
            out[0] = box_loss; out[1] = cls; out[2] = box_loss + cls;
        }
        return;
    }

    // ---- P1: top-12-bit count hist, LDS replicated, merge to global replica ----
#pragma unroll
    for (int j = 0; j < 8; ++j) {
        unsigned b = vb[j];
        if (b != MARK) atomicAdd(&hrep[rep][b >> 20], 1u);
    }
    __syncthreads();
    {
        unsigned* g = ws + OFF_H1C + (blockIdx.x & 3) * 4096;
#pragma unroll
        for (int i = 0; i < 4; ++i) {
            int bkt = t * 4 + i;
            unsigned c = hrep[0][bkt] + hrep[1][bkt] + hrep[2][bkt] + hrep[3][bkt];
            if (c) atomicAdd(g + bkt, c);   // chains <= 4 deep (4 blocks/replica)
        }
    }
    unsigned phase = 1;
    gbar(ws, phase);

    // parallel cutoff select over 4096 merged buckets (identical in all blocks);
    // suffix scan via wave shuffles + 16 wave totals (2 syncthreads total)
    auto sel12 = [&](int off, int target) {
        unsigned c4[4] = {0u, 0u, 0u, 0u};
#pragma unroll
        for (int r = 0; r < 4; ++r) {
            uint4 u = reinterpret_cast<const uint4*>(ws + off + r * 4096)[t];
            c4[0] += u.x; c4[1] += u.y; c4[2] += u.z; c4[3] += u.w;
        }
        int cc = (int)(c4[0] + c4[1] + c4[2] + c4[3]);
        int v = cc;
#pragma unroll
        for (int o = 1; o < 64; o <<= 1) {       // wave-local suffix-inclusive
            int u2 = __shfl_down(v, o);
            if (lane + o < 64) v += u2;
        }
        if (lane == 0) wtot[wave] = v;
        __syncthreads();
        int S = v;
        for (int w = wave + 1; w < 16; ++w) S += wtot[w];
        if (S >= target && S - cc < target) {     // exactly one thread
            int cum = S - cc;                     // count above this thread's strip
            for (int b = 3; b >= 0; --b) {
                int cb = (int)c4[b];
                if (cum + cb >= target) { sh[0] = t * 4 + b; sh[1] = target - cum; sh[2] = cb; break; }
                cum += cb;
            }
        }
        __syncthreads();   // sh visible; wtot reusable
    };

    sel12(OFF_H1C, k);
    int b1 = sh[0], r1 = sh[1];
    unsigned THR = 0; int ge = 0, rrem = 0, resolved = 0;
    if (sh[1] == sh[2]) { THR = (unsigned)b1 << 20; ge = 1; resolved = 1; }

    if (!resolved) {
        // ---- P2: mid-12-bit hist within bucket b1 ----
        for (int i = t; i < 16384; i += 1024) hflat[i] = 0u;
        __syncthreads();
#pragma unroll
        for (int j = 0; j < 8; ++j) {
            unsigned b = vb[j];   // marker top12 = 4095 > any valid (<= ~1048)
            if ((int)(b >> 20) == b1) atomicAdd(&hrep[rep][(b >> 8) & 0xFFFu], 1u);
        }
        __syncthreads();
        {
            unsigned* g = ws + OFF_H2C + (blockIdx.x & 3) * 4096;
#pragma unroll
            for (int i = 0; i < 4; ++i) {
                int bkt = t * 4 + i;
                unsigned c = hrep[0][bkt] + hrep[1][bkt] + hrep[2][bkt] + hrep[3][bkt];
                if (c) atomicAdd(g + bkt, c);
            }
        }
        gbar(ws, ++phase);
        sel12(OFF_H2C, r1);
        int b2 = sh[0], r2 = sh[1];
        unsigned pfx = ((unsigned)b1 << 12) | (unsigned)b2;
        if (sh[1] == sh[2]) { THR = pfx << 8; ge = 1; resolved = 1; }

        if (!resolved) {
            // ---- P3: low-8-bit hist within 24-bit prefix ----
            for (int i = t; i < 16384; i += 1024) hflat[i] = 0u;
            __syncthreads();
#pragma unroll
            for (int j = 0; j < 8; ++j) {
                unsigned b = vb[j];
                if ((b >> 8) == pfx) atomicAdd(&hrep[rep][b & 0xFFu], 1u);
            }
            __syncthreads();
            if (t < 256) {
                unsigned c = hrep[0][t] + hrep[1][t] + hrep[2][t] + hrep[3][t];
                if (c) atomicAdd(ws + OFF_H3C + (blockIdx.x & 3) * 256 + t, c);
            }
            gbar(ws, ++phase);
            int c = 0;
            if (t < 256)
                for (int r = 0; r < 4; ++r) c += (int)ws[OFF_H3C + r * 256 + t];
            int v = c;
#pragma unroll
            for (int o = 1; o < 64; o <<= 1) {
                int u2 = __shfl_down(v, o);
                if (lane + o < 64) v += u2;
            }
            if (lane == 0) wtot[wave] = v;
            __syncthreads();
            int S = v;
            for (int w = wave + 1; w < 16; ++w) S += wtot[w];
            if (S >= r2 && S - c < r2) { sh[0] = t; sh[1] = r2 - (S - c); }
            __syncthreads();
            THR = (pfx << 8) | (unsigned)sh[0];
            rrem = sh[1];
            ge = 0;
        }
    }

    // ---- FINAL: per-block register sum of selected candidates ----
    float loc = 0.f;
#pragma unroll
    for (int j = 0; j < 8; ++j) {
        unsigned b = vb[j];
        if (b != MARK && (ge ? (b >= THR) : (b > THR))) loc += __uint_as_float(b);
    }
#pragma unroll
    for (int o = 32; o; o >>= 1) loc += __shfl_down(loc, o);
    if (lane == 0) s_wf[wave][0] = loc;
    __syncthreads();
    if (t == 0) {
        float s = 0.f;
        for (int w = 0; w < 16; ++w) s += s_wf[w][0];
        ((float*)ws)[OFF_FSL + blockIdx.x] = s;
    }
    gbar(ws, ++phase);
    if (b0 && t < 64) {
        float s = (t < NBLK) ? ((const float*)ws)[OFF_FSL + t] : 0.f;
#pragma unroll
        for (int o = 32; o; o >>= 1) s += __shfl_down(s, o);
        if (t == 0) {
            float sneg = s + (ge ? 0.f : (float)rrem * __uint_as_float(THR));
            float cls = 10.0f * (fp + sneg) / fmaxf(fw + (float)k, 1e-6f) / denom;
            out[0] = box_loss; out[1] = cls; out[2] = box_loss + cls;
        }
    }
}

extern "C" void kernel_launch(void* const* d_in, const int* in_sizes, int n_in,
                              void* d_out, int out_size, void* d_ws, size_t ws_size,
                              hipStream_t stream)
{
    const float* pred_boxes   = (const float*)d_in[0];
    const float* pred_classes = (const float*)d_in[1];
    const float* true_boxes   = (const float*)d_in[2];
    const int*   true_classes = (const int*)d_in[3];
    const float* anchors      = (const float*)d_in[4];
    unsigned int* ws = (unsigned int*)d_ws;

    dl_main<<<NTOT / 256, 256, 0, stream>>>(pred_boxes, pred_classes, true_boxes,
                                            true_classes, anchors, ws);
    dl_select<<<NBLK, 1024, 0, stream>>>(ws, (float*)d_out);
}